// Round 4
// baseline (379.378 us; speedup 1.0000x reference)
//
#include <hip/hip_runtime.h>

// GCN: h1 = relu(Agg(x@W1)+b1); h2 = relu(Agg(h1@W2)+b2); out = mean(h2)@Wc+bc
// Agg uses norm(r,c)=dinv[r]*dinv[c] which factors: prescale rows by dinv in
// GEMM epilogue, pull-accumulate via CSR (built per call), postscale+bias+relu.
// R1: k_agg MLP — float4 lanes, half-wave/edge, 4-deep unroll.
// R2: edge-kernel ×4 ILP — NEUTRAL (falsified latency theory).
// R3: CSR build is atomic-LINE-CONTENTION bound (256 incr/line). Split into
//     8 plane-private histograms/cursors (plane = eighth of edge list),
//     scan over 400k (c,k)-ordered bins => contention /8, CSR still c-contig.

constexpr int N = 50000;
constexpr int E = 800000;
constexpr int D = 128;
constexpr int DOUT = 40;
constexpr int P = 8;                 // planes
constexpr int T8 = E / P;            // 100000 edge threads
constexpr int NBINS = N * P;         // 400000
constexpr int NB1 = (NBINS + 1023) / 1024;   // 391 scan blocks

// ---------------- CSR build (8-plane counting sort) ----------------
__global__ void k_count(const int* __restrict__ col, int* __restrict__ cnt8) {
    int t = blockIdx.x * 256 + threadIdx.x;
    if (t >= T8) return;
#pragma unroll
    for (int i = 0; i < P; ++i) {
        int c = col[t + i * T8];
        atomicAdd(&cnt8[i * N + c], 1);
    }
}

// bins ordered b = c*8+k; value read from plane-major cnt8[k*N+c]
__global__ void k_scan1(const int* __restrict__ cnt8, int* __restrict__ ofs,
                        int* __restrict__ bsum) {
    __shared__ int buf[1024];
    int t = threadIdx.x;
    int i = blockIdx.x * 1024 + t;
    int v = 0;
    if (i < NBINS) v = cnt8[(i & 7) * N + (i >> 3)];
    buf[t] = v;
    __syncthreads();
    for (int d = 1; d < 1024; d <<= 1) {
        int add = (t >= d) ? buf[t - d] : 0;
        __syncthreads();
        buf[t] += add;
        __syncthreads();
    }
    if (i < NBINS) ofs[i] = buf[t] - v;        // block-local exclusive
    if (t == 1023) bsum[blockIdx.x] = buf[1023];
}

__global__ void k_scan2(int* __restrict__ bsum) {   // 1 block, 512 threads
    __shared__ int buf[512];
    int t = threadIdx.x;
    int v = (t < NB1) ? bsum[t] : 0;
    buf[t] = v;
    __syncthreads();
    for (int d = 1; d < 512; d <<= 1) {
        int add = (t >= d) ? buf[t - d] : 0;
        __syncthreads();
        buf[t] += add;
        __syncthreads();
    }
    if (t < NB1) bsum[t] = buf[t] - v;         // exclusive over block sums
}

// binofs[b] (bin-major) and cursor8 (plane-major, aliases cnt8 storage)
__global__ void k_scan3(int* __restrict__ ofs, int* __restrict__ cursor8,
                        const int* __restrict__ bsum, int* __restrict__ binofs) {
    int i = blockIdx.x * 1024 + threadIdx.x;
    if (i < NBINS) {
        int o = ofs[i] + bsum[blockIdx.x];
        binofs[i] = o;
        cursor8[(i & 7) * N + (i >> 3)] = o;
    }
}

__global__ void k_node(const int* __restrict__ binofs, int* __restrict__ nodeofs,
                       float* __restrict__ dinv) {
    int c = blockIdx.x * 256 + threadIdx.x;
    if (c >= N) return;
    int e0 = binofs[c * P];
    int e1 = (c == N - 1) ? E : binofs[(c + 1) * P];
    nodeofs[c] = e0;
    dinv[c] = rsqrtf((float)(e1 - e0 + 1));    // +1 self loop; always > 0
    if (c == 0) nodeofs[N] = E;
}

__global__ void k_bucket(const int* __restrict__ ei, int* __restrict__ cursor8,
                         int* __restrict__ csr) {
    int t = blockIdx.x * 256 + threadIdx.x;
    if (t >= T8) return;
#pragma unroll
    for (int i = 0; i < P; ++i) {
        int e = t + i * T8;
        int c = ei[E + e];
        int r = ei[e];
        int p = atomicAdd(&cursor8[i * N + c], 1);
        csr[p] = r;
    }
}

// ---------------- GEMM: out[r] = dinv[r] * (A[r] @ W), A: [M x 128], W: [128 x 128]
__global__ __launch_bounds__(256) void k_gemm(const float* __restrict__ A,
                                              const float* __restrict__ W,
                                              const float* __restrict__ dinv,
                                              float* __restrict__ out, int M) {
    __shared__ float As[32][128];   // [k][row]
    __shared__ float Bs[32][128];   // [k][col]
    int tid = threadIdx.x;
    int tx = tid & 15, ty = tid >> 4;
    int row0 = blockIdx.x * 128;
    float acc[8][8] = {};

    for (int kt = 0; kt < 128; kt += 32) {
        {
            int r = tid >> 1;
            int kk = (tid & 1) * 16;
            int grow = row0 + r;
#pragma unroll
            for (int q = 0; q < 4; ++q) {
                float4 v = make_float4(0.f, 0.f, 0.f, 0.f);
                if (grow < M) v = *(const float4*)&A[(size_t)grow * D + kt + kk + q * 4];
                As[kk + q * 4 + 0][r] = v.x;
                As[kk + q * 4 + 1][r] = v.y;
                As[kk + q * 4 + 2][r] = v.z;
                As[kk + q * 4 + 3][r] = v.w;
            }
        }
        {
            int kb = tid >> 3;
            int cb = (tid & 7) * 16;
#pragma unroll
            for (int q = 0; q < 4; ++q) {
                *(float4*)&Bs[kb][cb + q * 4] =
                    *(const float4*)&W[(size_t)(kt + kb) * D + cb + q * 4];
            }
        }
        __syncthreads();
#pragma unroll
        for (int k = 0; k < 32; ++k) {
            float a[8], b[8];
            *(float4*)&a[0] = *(const float4*)&As[k][ty * 8];
            *(float4*)&a[4] = *(const float4*)&As[k][ty * 8 + 4];
            *(float4*)&b[0] = *(const float4*)&Bs[k][tx * 8];
            *(float4*)&b[4] = *(const float4*)&Bs[k][tx * 8 + 4];
#pragma unroll
            for (int i = 0; i < 8; ++i)
#pragma unroll
                for (int j = 0; j < 8; ++j)
                    acc[i][j] = fmaf(a[i], b[j], acc[i][j]);
        }
        __syncthreads();
    }

#pragma unroll
    for (int i = 0; i < 8; ++i) {
        int r = row0 + ty * 8 + i;
        if (r < M) {
            float s = dinv[r];
#pragma unroll
            for (int j = 0; j < 8; j += 4) {
                float4 v;
                v.x = acc[i][j + 0] * s;
                v.y = acc[i][j + 1] * s;
                v.z = acc[i][j + 2] * s;
                v.w = acc[i][j + 3] * s;
                *(float4*)&out[(size_t)r * D + tx * 8 + j] = v;
            }
        }
    }
}

// ---------------- Aggregation (pull, 1 wave per node, MLP-optimized) ------
__device__ __forceinline__ void f4add(float4& a, const float4& v) {
    a.x += v.x; a.y += v.y; a.z += v.z; a.w += v.w;
}

__global__ __launch_bounds__(256) void k_agg(const float4* __restrict__ hs4,
                                             const int* __restrict__ ofs,
                                             const int* __restrict__ csr,
                                             const float* __restrict__ dinv,
                                             const float4* __restrict__ bias4,
                                             float4* __restrict__ out4) {
    int wave = threadIdx.x >> 6;
    int lane = threadIdx.x & 63;
    int h = lane >> 5;          // half-wave id 0/1
    int q = lane & 31;          // float4 column
    int c = blockIdx.x * 4 + wave;
    if (c >= N) return;
    int e0 = ofs[c], e1 = ofs[c + 1];

    float4 z = make_float4(0.f, 0.f, 0.f, 0.f);
    float4 a0 = z, a1 = z, a2 = z, a3 = z;
    if (h == 0) a0 = hs4[(size_t)c * 32 + q];        // self loop on half 0

    int j = e0;
    for (; j + 8 <= e1; j += 8) {
        int r0 = csr[j + 0 + h];
        int r1 = csr[j + 2 + h];
        int r2 = csr[j + 4 + h];
        int r3 = csr[j + 6 + h];
        float4 v0 = hs4[(size_t)r0 * 32 + q];
        float4 v1 = hs4[(size_t)r1 * 32 + q];
        float4 v2 = hs4[(size_t)r2 * 32 + q];
        float4 v3 = hs4[(size_t)r3 * 32 + q];
        f4add(a0, v0); f4add(a1, v1); f4add(a2, v2); f4add(a3, v3);
    }
    if (j + 4 <= e1) {
        int r0 = csr[j + 0 + h];
        int r1 = csr[j + 2 + h];
        float4 v0 = hs4[(size_t)r0 * 32 + q];
        float4 v1 = hs4[(size_t)r1 * 32 + q];
        f4add(a0, v0); f4add(a1, v1);
        j += 4;
    }
    if (j + 2 <= e1) {
        int r0 = csr[j + h];
        float4 v0 = hs4[(size_t)r0 * 32 + q];
        f4add(a0, v0);
        j += 2;
    }
    if (j < e1 && h == 0) {
        int r0 = csr[j];
        float4 v0 = hs4[(size_t)r0 * 32 + q];
        f4add(a0, v0);
    }

    f4add(a0, a1); f4add(a2, a3); f4add(a0, a2);
    a0.x += __shfl_xor(a0.x, 32, 64);
    a0.y += __shfl_xor(a0.y, 32, 64);
    a0.z += __shfl_xor(a0.z, 32, 64);
    a0.w += __shfl_xor(a0.w, 32, 64);

    if (h == 0) {
        float dc = dinv[c];
        float4 b = bias4[q];
        float4 o;
        o.x = fmaxf(fmaf(dc, a0.x, b.x), 0.f);
        o.y = fmaxf(fmaf(dc, a0.y, b.y), 0.f);
        o.z = fmaxf(fmaf(dc, a0.z, b.z), 0.f);
        o.w = fmaxf(fmaf(dc, a0.w, b.w), 0.f);
        out4[(size_t)c * 32 + q] = o;
    }
}

// ---------------- Mean pool (stage 1) ----------------
__global__ __launch_bounds__(256) void k_pool(const float* __restrict__ h,
                                              float* __restrict__ gpart) {
    int d = threadIdx.x & 127;
    int half = threadIdx.x >> 7;
    int b = blockIdx.x;                 // 256 blocks
    int per = (N + 255) / 256;          // 196
    int r0 = b * per;
    int r1 = r0 + per;
    if (r1 > N) r1 = N;
    float acc = 0.f;
    for (int r = r0 + half; r < r1; r += 2)
        acc += h[(size_t)r * D + d];
    __shared__ float red[256];
    red[threadIdx.x] = acc;
    __syncthreads();
    if (half == 0) gpart[(size_t)b * D + d] = red[d] + red[128 + d];
}

// ---------------- Final: g = sum(gpart)/N; out = g@Wc + bc  (512 threads)
__global__ __launch_bounds__(512) void k_final(const float* __restrict__ gpart,
                                               const float* __restrict__ Wc,
                                               const float* __restrict__ bc,
                                               float* __restrict__ out) {
    __shared__ float g[D];
    __shared__ float red[512];
    int t = threadIdx.x;
    int d = t & 127, grp = t >> 7;      // 4 groups, 64 partials each
    float s = 0.f;
#pragma unroll 4
    for (int w = grp * 64; w < grp * 64 + 64; ++w)
        s += gpart[(size_t)w * D + d];
    red[t] = s;
    __syncthreads();
    if (grp == 0)
        g[d] = (red[d] + red[128 + d] + red[256 + d] + red[384 + d]) * (1.0f / (float)N);
    __syncthreads();
    if (t < DOUT) {
        float acc = bc[t];
        for (int dd = 0; dd < D; ++dd) acc = fmaf(g[dd], Wc[dd * DOUT + t], acc);
        out[t] = acc;
    }
}

extern "C" void kernel_launch(void* const* d_in, const int* in_sizes, int n_in,
                              void* d_out, int out_size, void* d_ws, size_t ws_size,
                              hipStream_t stream) {
    const float* x  = (const float*)d_in[0];
    const int*   ei = (const int*)d_in[1];
    const float* W1 = (const float*)d_in[2];
    const float* b1 = (const float*)d_in[3];
    const float* W2 = (const float*)d_in[4];
    const float* b2 = (const float*)d_in[5];
    const float* Wc = (const float*)d_in[6];
    const float* bc = (const float*)d_in[7];
    float* out = (float*)d_out;

    char* ws = (char*)d_ws;
    size_t off = 0;
    auto alloc = [&](size_t bytes) {
        void* p = ws + off;
        off += (bytes + 511) & ~(size_t)511;
        return p;
    };
    int*   cnt8    = (int*)  alloc((size_t)NBINS * 4);   // reused as cursor8
    int*   ofs     = (int*)  alloc((size_t)NBINS * 4);   // scan scratch
    int*   binofs  = (int*)  alloc((size_t)NBINS * 4);
    int*   nodeofs = (int*)  alloc((size_t)(N + 1) * 4);
    float* dinv    = (float*)alloc((size_t)N * 4);
    int*   bsum    = (int*)  alloc(512 * 4);
    int*   csr     = (int*)  alloc((size_t)E * 4);
    float* hsA     = (float*)alloc((size_t)N * D * 4);
    float* hactB   = (float*)alloc((size_t)N * D * 4);
    float* gpart   = (float*)alloc((size_t)256 * D * 4);
    (void)ws_size; (void)in_sizes; (void)n_in; (void)out_size;

    const int* col = ei + E;

    hipMemsetAsync(cnt8, 0, (size_t)NBINS * 4, stream);

    int gT = (T8 + 255) / 256;   // 391
    k_count<<<gT, 256, 0, stream>>>(col, cnt8);
    k_scan1<<<NB1, 1024, 0, stream>>>(cnt8, ofs, bsum);
    k_scan2<<<1, 512, 0, stream>>>(bsum);
    k_scan3<<<NB1, 1024, 0, stream>>>(ofs, cnt8 /*cursor8*/, bsum, binofs);
    k_node<<<(N + 255) / 256, 256, 0, stream>>>(binofs, nodeofs, dinv);
    k_bucket<<<gT, 256, 0, stream>>>(ei, cnt8 /*cursor8*/, csr);

    int gM = (N + 127) / 128;   // 391
    int gA = (N + 3) / 4;       // 12500

    // layer 1
    k_gemm<<<gM, 256, 0, stream>>>(x, W1, dinv, hsA, N);
    k_agg<<<gA, 256, 0, stream>>>((const float4*)hsA, nodeofs, csr, dinv,
                                  (const float4*)b1, (float4*)hactB);
    // layer 2
    k_gemm<<<gM, 256, 0, stream>>>(hactB, W2, dinv, hsA, N);
    k_agg<<<gA, 256, 0, stream>>>((const float4*)hsA, nodeofs, csr, dinv,
                                  (const float4*)b2, (float4*)hactB);
    // pool + classify
    k_pool<<<256, 256, 0, stream>>>(hactB, gpart);
    k_final<<<1, 512, 0, stream>>>(gpart, Wc, bc, out);
}